// Round 1
// baseline (129.388 us; speedup 1.0000x reference)
//
#include <hip/hip_runtime.h>

#define NA   512      // atoms per batch
#define NB   4        // batches
#define NZT  95       // table size per species dim

// ---------------------------------------------------------------------------
// Kernel 1: coordination numbers cn[b*NA+i]. One wave (64 lanes) per atom.
// ---------------------------------------------------------------------------
__global__ void __launch_bounds__(64) cn_kernel(
    const float* __restrict__ coord,    // (NB, NA, 3)
    const int*   __restrict__ numbers,  // (NB, NA)
    const float* __restrict__ rcov,     // (NZT,)
    float*       __restrict__ cn)       // (NB*NA,)
{
    const int bi   = blockIdx.x;            // 0 .. NB*NA-1
    const int b    = bi >> 9;               // / NA
    const int i    = bi & (NA - 1);
    const int lane = threadIdx.x;

    const float* cb = coord   + (size_t)b * NA * 3;
    const int*   nb = numbers + (size_t)b * NA;

    const float xi  = cb[3 * i + 0];
    const float yi  = cb[3 * i + 1];
    const float zi  = cb[3 * i + 2];
    const float rci = rcov[nb[i]];

    float acc = 0.0f;
    #pragma unroll
    for (int t = 0; t < NA / 64; ++t) {
        const int j = lane + t * 64;
        if (j == i) continue;
        const float dx = xi - cb[3 * j + 0];
        const float dy = yi - cb[3 * j + 1];
        const float dz = zi - cb[3 * j + 2];
        const float r2 = dx * dx + dy * dy + dz * dz;
        const float r_ang = sqrtf(r2);
        if (r_ang <= 15.0f) {
            const float rb  = r_ang * 1.8897261258369282f;   // bohr
            const float rco = rci + rcov[nb[j]];
            // sigmoid: 1/(1+exp(-K1*(rco/r - 1))); inf/0 edge cases match ref
            acc += 1.0f / (1.0f + __expf(-16.0f * (rco / rb - 1.0f)));
        }
    }
    #pragma unroll
    for (int off = 32; off > 0; off >>= 1)
        acc += __shfl_down(acc, off, 64);
    if (lane == 0) cn[bi] = acc;
}

// ---------------------------------------------------------------------------
// Kernel 2: pair energies. One thread per ordered pair (b,i,j).
// Block = 256 threads = one (b,i) with 256 consecutive j (N=512 -> 2 blocks/row).
// ---------------------------------------------------------------------------
__global__ void __launch_bounds__(256) energy_kernel(
    const float* __restrict__ coord,    // (NB, NA, 3)
    const int*   __restrict__ numbers,  // (NB, NA)
    const float* __restrict__ r4r2,     // (NZT,)
    const float* __restrict__ c6ab,     // (NZT, NZT, 5, 5)
    const float* __restrict__ cn_ref,   // (NZT, NZT, 5, 5)
    const float* __restrict__ cn,       // (NB*NA,)
    float*       __restrict__ out)      // (NB,)
{
    const int tid = blockIdx.x * 256 + threadIdx.x;
    const int b   = tid >> 18;                 // / (NA*NA)
    const int rem = tid & (NA * NA - 1);
    const int i   = rem >> 9;                  // / NA
    const int j   = rem & (NA - 1);

    float e = 0.0f;
    if (i != j) {
        const float* cb = coord + (size_t)b * NA * 3;
        const float dx = cb[3 * i + 0] - cb[3 * j + 0];
        const float dy = cb[3 * i + 1] - cb[3 * j + 1];
        const float dz = cb[3 * i + 2] - cb[3 * j + 2];
        const float r2 = dx * dx + dy * dy + dz * dz;
        const float r_ang = sqrtf(r2);
        if (r_ang <= 15.0f) {
            const int* nb = numbers + (size_t)b * NA;
            const int zi = nb[i];
            const int zj = nb[j];
            const float cni = cn[b * NA + i];
            const float cnj = cn[b * NA + j];

            const float* c6p  = c6ab   + ((size_t)zi * NZT + zj) * 25;
            const float* cnip = cn_ref + ((size_t)zi * NZT + zj) * 25;
            const float* cnjp = cn_ref + ((size_t)zj * NZT + zi) * 25;  // transposed access

            float wsum = 0.0f, c6w = 0.0f;
            #pragma unroll
            for (int a = 0; a < 5; ++a) {
                #pragma unroll
                for (int b2 = 0; b2 < 5; ++b2) {
                    const float c6r = c6p[a * 5 + b2];
                    const float di  = cni - cnip[a * 5 + b2];
                    const float dj  = cnj - cnjp[b2 * 5 + a];   // swapaxes(-1,-2)
                    float w = __expf(-4.0f * (di * di + dj * dj));
                    w = (c6r > 0.0f) ? w : 0.0f;
                    wsum += w;
                    c6w  += c6r * w;
                }
            }
            const float c6 = c6w / (wsum + 1e-20f);

            const float rrij = r4r2[zi] * r4r2[zj];
            const float c8   = 3.0f * c6 * rrij;
            const float r0   = sqrtf(3.0f * rrij);
            const float f    = 0.4145f * r0 + 4.8593f;

            const float B2  = 1.8897261258369282f * 1.8897261258369282f;
            const float r2b = r2 * B2;            // r_bohr^2
            const float r6  = r2b * r2b * r2b;    // r_bohr^6
            const float r8  = r6 * r2b;           // r_bohr^8
            const float f2  = f * f;
            const float f6  = f2 * f2 * f2;
            const float f8  = f6 * f2;

            float ep = 1.0f * c6 / (r6 + f6) + 1.2177f * c8 / (r8 + f8);

            // smooth cutoff switch on r_ang in [12, 15]
            float x = (r_ang - 12.0f) * (1.0f / 3.0f);
            x = fminf(fmaxf(x, 0.0f), 1.0f);
            const float sw = 1.0f - x * x * (3.0f - 2.0f * x);
            e = ep * sw;
        }
    }

    // block reduction: wave shuffle then cross-wave via LDS
    #pragma unroll
    for (int off = 32; off > 0; off >>= 1)
        e += __shfl_down(e, off, 64);

    __shared__ float red[4];
    const int wave = threadIdx.x >> 6;
    if ((threadIdx.x & 63) == 0) red[wave] = e;
    __syncthreads();
    if (threadIdx.x == 0) {
        const float s = red[0] + red[1] + red[2] + red[3];
        atomicAdd(&out[b], s * (-0.5f * 27.211386245988f));
    }
}

// ---------------------------------------------------------------------------
extern "C" void kernel_launch(void* const* d_in, const int* in_sizes, int n_in,
                              void* d_out, int out_size, void* d_ws, size_t ws_size,
                              hipStream_t stream) {
    const float* coord   = (const float*)d_in[0];
    const int*   numbers = (const int*)  d_in[1];
    const float* rcov    = (const float*)d_in[2];
    const float* r4r2    = (const float*)d_in[3];
    const float* c6ab    = (const float*)d_in[4];
    const float* cn_ref  = (const float*)d_in[5];
    float* out = (float*)d_out;
    float* cn  = (float*)d_ws;   // NB*NA floats = 8 KB

    hipMemsetAsync(out, 0, (size_t)out_size * sizeof(float), stream);

    cn_kernel<<<NB * NA, 64, 0, stream>>>(coord, numbers, rcov, cn);

    const int total = NB * NA * NA;
    energy_kernel<<<total / 256, 256, 0, stream>>>(coord, numbers, r4r2, c6ab,
                                                   cn_ref, cn, out);
}